// Round 2
// baseline (243.181 us; speedup 1.0000x reference)
//
#include <hip/hip_runtime.h>
#include <cstdint>
#include <cstddef>

// ---- problem constants ----
#define SEQ   920
#define DM    1536
#define DH    384
#define NHD   4
#define NB    4
#define NBH   16          // NB*NHD
#define MTOK  3680        // NB*SEQ
#define NREL  1839        // 2*920-1

typedef short          bf16x8 __attribute__((ext_vector_type(8)));
typedef float          f32x4  __attribute__((ext_vector_type(4)));
typedef unsigned short u16x4  __attribute__((ext_vector_type(4)));

__device__ __forceinline__ unsigned short f2bf(float f){
  union{float f; unsigned u;} v; v.f = f;
  unsigned r = v.u + 0x7FFFu + ((v.u >> 16) & 1u);
  return (unsigned short)(r >> 16);
}
__device__ __forceinline__ float bf2f(unsigned short h){
  union{unsigned u; float f;} v; v.u = ((unsigned)h) << 16;
  return v.f;
}
__device__ __forceinline__ f32x4 mfma_bf16(bf16x8 a, bf16x8 b, f32x4 c){
  return __builtin_amdgcn_mfma_f32_16x16x32_bf16(a, b, c, 0, 0, 0);
}
__device__ __forceinline__ void gload_lds16(const void* g, void* l){
  __builtin_amdgcn_global_load_lds((const __attribute__((address_space(1))) void*)g,
                                   (__attribute__((address_space(3))) void*)l, 16, 0, 0);
}

// ---------------- convert f32 -> bf16 (n % 4 == 0) ----------------
__global__ __launch_bounds__(256) void k_f2bf(const float* __restrict__ src,
                                              unsigned short* __restrict__ dst, int n){
  int i = (blockIdx.x * 256 + threadIdx.x) * 4;
  int stride = gridDim.x * 256 * 4;
  for(; i + 3 < n; i += stride){
    f32x4 v = *(const f32x4*)(src + i);
    u16x4 o; o.x = f2bf(v.x); o.y = f2bf(v.y); o.z = f2bf(v.z); o.w = f2bf(v.w);
    *(u16x4*)(dst + i) = o;
  }
}

// ---------------- transpose+convert weights: W[k][n] f32 -> Wt[which*1536+n][k] bf16 ----
__global__ __launch_bounds__(256) void k_wt(const float* __restrict__ w,
                                            unsigned short* __restrict__ wt, int which){
  __shared__ float t[32][33];
  int k0 = blockIdx.x * 32, n0 = blockIdx.y * 32;
  int tx = threadIdx.x, ty = threadIdx.y;       // (32,8)
  #pragma unroll
  for(int j = 0; j < 4; j++)
    t[ty*4+j][tx] = w[(size_t)(k0 + ty*4 + j) * DM + n0 + tx];
  __syncthreads();
  #pragma unroll
  for(int j = 0; j < 4; j++)
    wt[(size_t)(which*DM + n0 + ty*4 + j) * DM + k0 + tx] = f2bf(t[tx][ty*4+j]);
}

// ---------------- 128x128 bf16 GEMM tile (m97 structure), B given as B^T (n-major, ldb=K) ----
template<class Epi>
__device__ __forceinline__ void gemm128(const unsigned short* A, int lda, int Amax,
                                        const unsigned short* B, int ldb, int Bmax,
                                        int K, int m0, int n0, Epi epi){
  __shared__ unsigned short As[128*32];
  __shared__ unsigned short Bs[128*32];
  const int tid = threadIdx.x, w = tid >> 6, l = tid & 63;
  const int lg = l >> 4, lo = l & 15;
  const int wm = (w >> 1) * 64, wn = (w & 1) * 64;
  f32x4 acc[4][4] = {};
  for(int k0 = 0; k0 < K; k0 += 32){
    __syncthreads();
    #pragma unroll
    for(int r = 0; r < 2; r++){
      int o = r*4096 + w*1024 + l*16;
      int row = o >> 6, c = o & 63;
      int ar = m0 + row; ar = ar < Amax ? ar : Amax - 1;
      gload_lds16((const char*)A + ((size_t)ar*lda + k0)*2 + c, (char*)As + o);
      int br = n0 + row; br = br < Bmax ? br : Bmax - 1;
      gload_lds16((const char*)B + ((size_t)br*ldb + k0)*2 + c, (char*)Bs + o);
    }
    __syncthreads();
    bf16x8 a[4], b[4];
    #pragma unroll
    for(int f = 0; f < 4; f++){
      a[f] = *(const bf16x8*)((const char*)As + (wm + f*16 + lo)*64 + lg*16);
      b[f] = *(const bf16x8*)((const char*)Bs + (wn + f*16 + lo)*64 + lg*16);
    }
    #pragma unroll
    for(int fi = 0; fi < 4; fi++)
      #pragma unroll
      for(int fj = 0; fj < 4; fj++)
        acc[fi][fj] = mfma_bf16(a[fi], b[fj], acc[fi][fj]);
  }
  #pragma unroll
  for(int fi = 0; fi < 4; fi++)
    #pragma unroll
    for(int fj = 0; fj < 4; fj++)
      #pragma unroll
      for(int i = 0; i < 4; i++){
        int m = m0 + wm + fi*16 + lg*4 + i;
        int n = n0 + wn + fj*16 + lo;
        epi(m, n, acc[fi][fj][i]);
      }
}

// ---------------- projection: C = X @ [qw kw vw], scatter to Qb/Kb (bh,s,d) and Vt (bh,d,s) ----
__global__ __launch_bounds__(256) void k_proj(const unsigned short* __restrict__ X,
                                              const unsigned short* __restrict__ Wt,
                                              unsigned short* __restrict__ Qb,
                                              unsigned short* __restrict__ Kb,
                                              unsigned short* __restrict__ Vt){
  int m0 = blockIdx.x * 128, n0 = blockIdx.y * 128;
  gemm128(X, DM, MTOK, Wt, DM, 3*DM, DM, m0, n0,
    [=] __device__ (int m, int n, float v){
      if(m >= MTOK) return;
      int b = m / SEQ, s = m % SEQ;
      int which = n / DM, r = n % DM, h = r / DH, d = r % DH;
      int bh = b * NHD + h;
      if(which == 0)      Qb[((size_t)bh*SEQ + s)*DH + d] = f2bf(v * 0.05103103630798287f);
      else if(which == 1) Kb[((size_t)bh*SEQ + s)*DH + d] = f2bf(v);
      else                Vt[((size_t)bh*DH + d)*SEQ + s] = f2bf(v);
    });
}

// ---------------- rel: C = Q_all @ E^T, banded epilogue -> relS[bh*920+q][k] ----
__global__ __launch_bounds__(256) void k_rel(const unsigned short* __restrict__ Qb,
                                             const unsigned short* __restrict__ E,
                                             unsigned short* __restrict__ relS){
  int m0 = blockIdx.x * 128, n0 = blockIdx.y * 128;
  gemm128(Qb, DH, NBH*SEQ, E, DH, NREL, DH, m0, n0,
    [=] __device__ (int m, int n, float v){
      int q = m % SEQ;
      int j = n - 919 + q;                  // j == k
      if(j < 0 || j >= SEQ) return;
      relS[(size_t)m*SEQ + j] = f2bf(v);
    });
}

// ---------------- fused attention ----------------
__global__ __launch_bounds__(256) void k_attn(const unsigned short* __restrict__ Qb,
                                              const unsigned short* __restrict__ Kb,
                                              const unsigned short* __restrict__ Vt,
                                              const unsigned short* __restrict__ relS,
                                              float* __restrict__ out){
  __shared__ unsigned short Ks[32*384];   // rows 768B, XOR-swizzled
  __shared__ unsigned short Vs[384*32];   // rows 64B (V^T tile)
  __shared__ unsigned short Pl[32*40];    // rows 80B
  __shared__ float sums[2][32];
  const int bh = blockIdx.y, qt = blockIdx.x, q0 = qt * 32;
  const int tid = threadIdx.x, w = tid >> 6, l = tid & 63;
  const int mi = w >> 1, ni = w & 1;
  const int lg = l >> 4, lo = l & 15;

  // hoist Q A-frags to registers (12 x 16B per lane)
  int qrow = q0 + mi*16 + lo; if(qrow > SEQ-1) qrow = SEQ-1;
  const char* Qrow = (const char*)(Qb + ((size_t)bh*SEQ + qrow)*DH);
  bf16x8 qf[12];
  #pragma unroll
  for(int ks = 0; ks < 12; ks++) qf[ks] = *(const bf16x8*)(Qrow + ks*64 + lg*16);

  f32x4 ctx[2][6] = {};
  float ps[4] = {0.f, 0.f, 0.f, 0.f};

  for(int kt = 0; kt < 29; kt++){
    const int k0 = kt * 32;
    __syncthreads();
    #pragma unroll
    for(int r = 0; r < 6; r++){
      int o = r*4096 + w*1024 + l*16;
      // K tile, swizzled source
      int row = o / 768, c = o - row*768;
      int csw = c ^ ((row & 7) << 4);
      int krow = k0 + row; if(krow > SEQ-1) krow = SEQ-1;
      gload_lds16((const char*)Kb + ((size_t)bh*SEQ + krow)*768 + csw, (char*)Ks + o);
      // V^T tile (rows d, 64B each)
      int d = o >> 6, c2 = o & 63;
      int vcol = k0*2 + c2; if(vcol > 1824) vcol = 1824;
      gload_lds16((const char*)Vt + ((size_t)bh*DH + d)*1840 + vcol, (char*)Vs + o);
    }
    __syncthreads();
    // S = Q K^T (each wave one 16x16 frag: rows mi, cols ni)
    f32x4 accs = {};
    const int krowB = ni*16 + lo;
    const char* KsB = (const char*)Ks + krowB*768;
    const int sw = (krowB & 7) << 4;
    #pragma unroll
    for(int ks = 0; ks < 12; ks++){
      bf16x8 bf = *(const bf16x8*)(KsB + ((ks*64 + lg*16) ^ sw));
      accs = mfma_bf16(qf[ks], bf, accs);
    }
    // + rel, exp (no max-sub), accumulate rowsums, stage P
    unsigned short ph[4];
    #pragma unroll
    for(int i = 0; i < 4; i++){
      int q = q0 + mi*16 + lg*4 + i; if(q > SEQ-1) q = SEQ-1;
      int k = k0 + ni*16 + lo;
      int kc = k > SEQ-1 ? SEQ-1 : k;
      float rl = bf2f(relS[((size_t)bh*SEQ + q)*SEQ + kc]);
      float p = __expf(accs[i] + rl);
      if(k >= SEQ) p = 0.f;
      ps[i] += p;
      ph[i] = f2bf(p);
    }
    #pragma unroll
    for(int i = 0; i < 4; i++)
      *(unsigned short*)((char*)Pl + (mi*16 + lg*4 + i)*80 + (ni*16 + lo)*2) = ph[i];
    __syncthreads();
    // PV: ctx[m2][nj] += P(32x32) @ V(32x96-slice per wave)
    bf16x8 pa0 = *(const bf16x8*)((char*)Pl + lo*80 + lg*16);
    bf16x8 pa1 = *(const bf16x8*)((char*)Pl + (16 + lo)*80 + lg*16);
    #pragma unroll
    for(int nj = 0; nj < 6; nj++){
      int d = w*96 + nj*16 + lo;
      bf16x8 vb = *(const bf16x8*)((char*)Vs + d*64 + lg*16);
      ctx[0][nj] = mfma_bf16(pa0, vb, ctx[0][nj]);
      ctx[1][nj] = mfma_bf16(pa1, vb, ctx[1][nj]);
    }
  }
  // row sums: reduce over 16 lanes of the group, combine the two ni halves via LDS
  #pragma unroll
  for(int i = 0; i < 4; i++){
    float v = ps[i];
    v += __shfl_xor(v, 1); v += __shfl_xor(v, 2);
    v += __shfl_xor(v, 4); v += __shfl_xor(v, 8);
    if(lo == 0) sums[ni][mi*16 + lg*4 + i] = v;
  }
  __syncthreads();
  const int b = bh >> 2, h = bh & 3;
  #pragma unroll
  for(int m2 = 0; m2 < 2; m2++){
    #pragma unroll
    for(int i = 0; i < 4; i++){
      int ql = m2*16 + lg*4 + i;
      int q = q0 + ql;
      if(q >= SEQ) continue;
      float inv = 1.0f / (sums[0][ql] + sums[1][ql]);
      #pragma unroll
      for(int nj = 0; nj < 6; nj++){
        int d = w*96 + nj*16 + lo;
        out[((size_t)(b*SEQ + q))*DM + h*DH + d] = ctx[m2][nj][i] * inv;
      }
    }
  }
}

extern "C" void kernel_launch(void* const* d_in, const int* in_sizes, int n_in,
                              void* d_out, int out_size, void* d_ws, size_t ws_size,
                              hipStream_t stream){
  const float* X  = (const float*)d_in[0];
  const float* qw = (const float*)d_in[1];
  const float* kw = (const float*)d_in[2];
  const float* vw = (const float*)d_in[3];
  const float* de = (const float*)d_in[4];
  float* out = (float*)d_out;
  char* ws = (char*)d_ws;

  // ws layout (bytes):
  // [0, 11304960)           Qb  bf16 (bh,s,d)
  // [11304960, 22609920)    Kb  bf16 (bh,s,d)
  // [22609920, 33914880)    Vt  bf16 (bh,d,s)
  // [33914880, 35327232)    Eb  bf16 (1839x384)
  // [35327232, 62412032)    regionR: Xb(11.3M)+Wt(14.2M) during proj, then relS(27.1M)
  unsigned short* Qb   = (unsigned short*)ws;
  unsigned short* Kb   = (unsigned short*)(ws + 11304960);
  unsigned short* Vt   = (unsigned short*)(ws + 22609920);
  unsigned short* Eb   = (unsigned short*)(ws + 33914880);
  char* regionR        = ws + 35327232;
  unsigned short* relS = (unsigned short*)regionR;
  unsigned short* Xb   = (unsigned short*)regionR;
  unsigned short* Wt   = (unsigned short*)(regionR + 11304960);

  k_f2bf<<<dim3(1024), dim3(256), 0, stream>>>(X,  Xb, MTOK*DM);
  k_f2bf<<<dim3(256),  dim3(256), 0, stream>>>(de, Eb, NREL*DH);
  k_wt<<<dim3(48,48), dim3(32,8), 0, stream>>>(qw, Wt, 0);
  k_wt<<<dim3(48,48), dim3(32,8), 0, stream>>>(kw, Wt, 1);
  k_wt<<<dim3(48,48), dim3(32,8), 0, stream>>>(vw, Wt, 2);
  k_proj<<<dim3(29,36), dim3(256), 0, stream>>>(Xb, Wt, Qb, Kb, Vt);
  k_rel<<<dim3(115,15), dim3(256), 0, stream>>>(Qb, Eb, relS);   // overwrites Xb/Wt (dead)
  k_attn<<<dim3(29,16), dim3(256), 0, stream>>>(Qb, Kb, Vt, relS, out);
}

// Round 3
// 212.276 us; speedup vs baseline: 1.1456x; 1.1456x over previous
//
#include <hip/hip_runtime.h>
#include <cstdint>
#include <cstddef>

// ---- problem constants ----
#define SEQ   920
#define DM    1536
#define DH    384
#define NHD   4
#define NB    4
#define NBH   16          // NB*NHD
#define MTOK  3680        // NB*SEQ
#define NREL  1839        // 2*920-1

typedef short          bf16x8 __attribute__((ext_vector_type(8)));
typedef float          f32x4  __attribute__((ext_vector_type(4)));
typedef unsigned short u16x4  __attribute__((ext_vector_type(4)));

__device__ __forceinline__ unsigned short f2bf(float f){
  union{float f; unsigned u;} v; v.f = f;
  unsigned r = v.u + 0x7FFFu + ((v.u >> 16) & 1u);
  return (unsigned short)(r >> 16);
}
__device__ __forceinline__ float bf2f(unsigned short h){
  union{unsigned u; float f;} v; v.u = ((unsigned)h) << 16;
  return v.f;
}
__device__ __forceinline__ f32x4 mfma_bf16(bf16x8 a, bf16x8 b, f32x4 c){
  return __builtin_amdgcn_mfma_f32_16x16x32_bf16(a, b, c, 0, 0, 0);
}
__device__ __forceinline__ void gload_lds16(const void* g, void* l){
  __builtin_amdgcn_global_load_lds((const __attribute__((address_space(1))) void*)g,
                                   (__attribute__((address_space(3))) void*)l, 16, 0, 0);
}

// ---------------- convert f32 -> bf16 (n % 4 == 0) ----------------
__global__ __launch_bounds__(256) void k_f2bf(const float* __restrict__ src,
                                              unsigned short* __restrict__ dst, int n){
  int i = (blockIdx.x * 256 + threadIdx.x) * 4;
  int stride = gridDim.x * 256 * 4;
  for(; i + 3 < n; i += stride){
    f32x4 v = *(const f32x4*)(src + i);
    u16x4 o; o.x = f2bf(v.x); o.y = f2bf(v.y); o.z = f2bf(v.z); o.w = f2bf(v.w);
    *(u16x4*)(dst + i) = o;
  }
}

// ---- transpose+convert all 3 weights: W[k][n] f32 -> Wt[z*1536+n][k] bf16 (z = blockIdx.z) ----
__global__ __launch_bounds__(256) void k_wt3(const float* __restrict__ qw,
                                             const float* __restrict__ kw,
                                             const float* __restrict__ vw,
                                             unsigned short* __restrict__ wt){
  __shared__ float t[32][33];
  const float* w = blockIdx.z == 0 ? qw : (blockIdx.z == 1 ? kw : vw);
  int k0 = blockIdx.x * 32, n0 = blockIdx.y * 32;
  int tx = threadIdx.x, ty = threadIdx.y;       // (32,8)
  #pragma unroll
  for(int j = 0; j < 4; j++)
    t[ty*4+j][tx] = w[(size_t)(k0 + ty*4 + j) * DM + n0 + tx];
  __syncthreads();
  #pragma unroll
  for(int j = 0; j < 4; j++)
    wt[(size_t)(blockIdx.z*DM + n0 + ty*4 + j) * DM + k0 + tx] = f2bf(t[tx][ty*4+j]);
}

// ================= 192x192 tile, BK=64, 8-wave, ring-3 counted-vmcnt GEMM =================
// B given as B^T (n-major, ldb = K-elements). Epi receives (m_base, n, f32x4) where the 4
// accumulator elements correspond to rows m_base..m_base+3.
template<class Epi>
__device__ __forceinline__ void gemm192(const unsigned short* __restrict__ A, int lda, int Amax,
                                        const unsigned short* __restrict__ B, int ldb, int Bmax,
                                        int K, int m0, int n0, Epi epi){
  __shared__ unsigned short As[3*192*64];   // 3 slots x 24KB, rows 128B, XOR-swizzled content
  __shared__ unsigned short Bs[3*192*64];
  const int tid = threadIdx.x;
  const int w = tid >> 6, l = tid & 63;
  const int lg = l >> 4, lo = l & 15;
  const int wm = w >> 2, wn = w & 3;        // wave grid 2(M) x 4(N); per-wave 96x48

  // staging sources: 3 rounds of 8KB per matrix per K-tile; lane's (row, slot) is constant,
  // global column-slot pre-swizzled so linear LDS + XOR-read reconstructs (m173/m201 pattern)
  const char* ga[3]; const char* gb[3];
  #pragma unroll
  for(int r = 0; r < 3; r++){
    int row = r*64 + (tid >> 3);
    int gslot = (tid & 7) ^ (row & 7);
    int ar = m0 + row; ar = ar < Amax ? ar : Amax - 1;
    ga[r] = (const char*)A + (size_t)ar*lda*2 + gslot*16;
    int br = n0 + row; br = br < Bmax ? br : Bmax - 1;
    gb[r] = (const char*)B + (size_t)br*ldb*2 + gslot*16;
  }
  const int ldst = tid * 16;

  auto stage = [&](int kt, int slot){
    size_t koff = (size_t)kt * 128;         // 64 cols * 2B
    #pragma unroll
    for(int r = 0; r < 3; r++){
      gload_lds16(ga[r] + koff, (char*)As + slot*24576 + r*8192 + ldst);
      gload_lds16(gb[r] + koff, (char*)Bs + slot*24576 + r*8192 + ldst);
    }
  };

  f32x4 acc[6][3] = {};
  const int sw = (lo & 7) << 4;

  auto compute = [&](int slot){
    const char* Ab = (const char*)As + slot*24576;
    const char* Bb = (const char*)Bs + slot*24576;
    bf16x8 af[6][2], bf[3][2];
    #pragma unroll
    for(int fi = 0; fi < 6; fi++){
      int row = wm*96 + fi*16 + lo;
      #pragma unroll
      for(int kk = 0; kk < 2; kk++)
        af[fi][kk] = *(const bf16x8*)(Ab + row*128 + ((kk*64 + lg*16) ^ sw));
    }
    #pragma unroll
    for(int fj = 0; fj < 3; fj++){
      int row = wn*48 + fj*16 + lo;
      #pragma unroll
      for(int kk = 0; kk < 2; kk++)
        bf[fj][kk] = *(const bf16x8*)(Bb + row*128 + ((kk*64 + lg*16) ^ sw));
    }
    __builtin_amdgcn_s_setprio(1);
    #pragma unroll
    for(int kk = 0; kk < 2; kk++)
      #pragma unroll
      for(int fi = 0; fi < 6; fi++)
        #pragma unroll
        for(int fj = 0; fj < 3; fj++)
          acc[fi][fj] = mfma_bf16(af[fi][kk], bf[fj][kk], acc[fi][fj]);
    __builtin_amdgcn_s_setprio(0);
  };

  const int nk = K >> 6;
  stage(0, 0);
  stage(1, 1);
  int st = 0;
  for(int t = 0; t < nk; t++){
    if(t + 2 < nk){
      int s2 = st + 2 >= 3 ? st - 1 : st + 2;
      stage(t + 2, s2);
      asm volatile("s_waitcnt vmcnt(12)" ::: "memory");  // tiles t+1,t+2 still in flight
    } else if(t + 1 < nk){
      asm volatile("s_waitcnt vmcnt(6)" ::: "memory");
    } else {
      asm volatile("s_waitcnt vmcnt(0)" ::: "memory");
    }
    __builtin_amdgcn_s_barrier();
    compute(st);
    __builtin_amdgcn_s_barrier();
    st = st + 1 >= 3 ? 0 : st + 1;
  }

  #pragma unroll
  for(int fi = 0; fi < 6; fi++)
    #pragma unroll
    for(int fj = 0; fj < 3; fj++){
      int m = m0 + wm*96 + fi*16 + lg*4;
      int n = n0 + wn*48 + fj*16 + lo;
      epi(m, n, acc[fi][fj]);
    }
}

// ---------------- projection: C = X @ [qw kw vw] -> Qb/Kb (bh,s,d), Vt (bh,d,s) ----------------
__global__ __launch_bounds__(512) void k_proj(const unsigned short* __restrict__ X,
                                              const unsigned short* __restrict__ Wt,
                                              unsigned short* __restrict__ Qb,
                                              unsigned short* __restrict__ Kb,
                                              unsigned short* __restrict__ Vt){
  int bid = blockIdx.x;                       // 480 blocks, 480 % 8 == 0
  int wg  = (bid & 7) * 60 + (bid >> 3);      // XCD-contiguous chunks
  int m0 = (wg % 20) * 192, n0 = (wg / 20) * 192;
  gemm192(X, DM, MTOK, Wt, DM, 3*DM, DM, m0, n0,
    [=] __device__ (int m, int n, f32x4 v4){
      if(m >= MTOK) return;                   // 4-row group fully in/out (both %4==0)
      int which = n / DM, r = n % DM, h = r / DH, d = r % DH;
      int b = m / SEQ, s = m % SEQ;           // 920%4==0 -> group stays in one b
      int bh = b * NHD + h;
      if(which == 2){
        u16x4 o;
        o.x = f2bf(v4.x); o.y = f2bf(v4.y); o.z = f2bf(v4.z); o.w = f2bf(v4.w);
        *(u16x4*)(Vt + ((size_t)bh*DH + d)*SEQ + s) = o;
      } else if(which == 0){
        #pragma unroll
        for(int i = 0; i < 4; i++)
          Qb[((size_t)bh*SEQ + s + i)*DH + d] = f2bf(v4[i] * 0.05103103630798287f);
      } else {
        #pragma unroll
        for(int i = 0; i < 4; i++)
          Kb[((size_t)bh*SEQ + s + i)*DH + d] = f2bf(v4[i]);
      }
    });
}

// ---------------- rel: C = Q_all @ E^T, banded epilogue -> relS[bh*920+q][k] ----------------
__global__ __launch_bounds__(512) void k_rel(const unsigned short* __restrict__ Qb,
                                             const unsigned short* __restrict__ E,
                                             unsigned short* __restrict__ relS){
  int m0 = blockIdx.x * 192, n0 = blockIdx.y * 192;
  // band skip: tile contributes iff some (q, n) has 0 <= n-919+q < 920
  int s0 = m0 % SEQ;
  int qlo = s0, qhi = s0 + 191;
  if(qhi >= SEQ){ qlo = 0; qhi = SEQ - 1; }   // tile straddles a bh boundary
  if(n0 + 191 < 919 - qhi || n0 > 1838 - qlo) return;
  gemm192(Qb, DH, NBH*SEQ, E, DH, NREL, DH, m0, n0,
    [=] __device__ (int m, int n, f32x4 v4){
      #pragma unroll
      for(int i = 0; i < 4; i++){
        int mi = m + i;
        if(mi >= NBH*SEQ) continue;
        int q = mi % SEQ;
        int j = n - 919 + q;                  // j == k
        if(j < 0 || j >= SEQ) continue;
        relS[(size_t)mi*SEQ + j] = f2bf(v4[i]);
      }
    });
}

// ---------------- fused attention (unchanged from passing round-2 kernel) ----------------
__global__ __launch_bounds__(256) void k_attn(const unsigned short* __restrict__ Qb,
                                              const unsigned short* __restrict__ Kb,
                                              const unsigned short* __restrict__ Vt,
                                              const unsigned short* __restrict__ relS,
                                              float* __restrict__ out){
  __shared__ unsigned short Ks[32*384];   // rows 768B, XOR-swizzled
  __shared__ unsigned short Vs[384*32];   // rows 64B (V^T tile)
  __shared__ unsigned short Pl[32*40];    // rows 80B
  __shared__ float sums[2][32];
  const int bh = blockIdx.y, qt = blockIdx.x, q0 = qt * 32;
  const int tid = threadIdx.x, w = tid >> 6, l = tid & 63;
  const int mi = w >> 1, ni = w & 1;
  const int lg = l >> 4, lo = l & 15;

  int qrow = q0 + mi*16 + lo; if(qrow > SEQ-1) qrow = SEQ-1;
  const char* Qrow = (const char*)(Qb + ((size_t)bh*SEQ + qrow)*DH);
  bf16x8 qf[12];
  #pragma unroll
  for(int ks = 0; ks < 12; ks++) qf[ks] = *(const bf16x8*)(Qrow + ks*64 + lg*16);

  f32x4 ctx[2][6] = {};
  float ps[4] = {0.f, 0.f, 0.f, 0.f};

  for(int kt = 0; kt < 29; kt++){
    const int k0 = kt * 32;
    __syncthreads();
    #pragma unroll
    for(int r = 0; r < 6; r++){
      int o = r*4096 + w*1024 + l*16;
      int row = o / 768, c = o - row*768;
      int csw = c ^ ((row & 7) << 4);
      int krow = k0 + row; if(krow > SEQ-1) krow = SEQ-1;
      gload_lds16((const char*)Kb + ((size_t)bh*SEQ + krow)*768 + csw, (char*)Ks + o);
      int d = o >> 6, c2 = o & 63;
      int vcol = k0*2 + c2; if(vcol > 1824) vcol = 1824;
      gload_lds16((const char*)Vt + ((size_t)bh*DH + d)*1840 + vcol, (char*)Vs + o);
    }
    __syncthreads();
    f32x4 accs = {};
    const int krowB = ni*16 + lo;
    const char* KsB = (const char*)Ks + krowB*768;
    const int sw = (krowB & 7) << 4;
    #pragma unroll
    for(int ks = 0; ks < 12; ks++){
      bf16x8 bf = *(const bf16x8*)(KsB + ((ks*64 + lg*16) ^ sw));
      accs = mfma_bf16(qf[ks], bf, accs);
    }
    unsigned short ph[4];
    #pragma unroll
    for(int i = 0; i < 4; i++){
      int q = q0 + mi*16 + lg*4 + i; if(q > SEQ-1) q = SEQ-1;
      int k = k0 + ni*16 + lo;
      int kc = k > SEQ-1 ? SEQ-1 : k;
      float rl = bf2f(relS[((size_t)bh*SEQ + q)*SEQ + kc]);
      float p = __expf(accs[i] + rl);
      if(k >= SEQ) p = 0.f;
      ps[i] += p;
      ph[i] = f2bf(p);
    }
    #pragma unroll
    for(int i = 0; i < 4; i++)
      *(unsigned short*)((char*)Pl + (mi*16 + lg*4 + i)*80 + (ni*16 + lo)*2) = ph[i];
    __syncthreads();
    bf16x8 pa0 = *(const bf16x8*)((char*)Pl + lo*80 + lg*16);
    bf16x8 pa1 = *(const bf16x8*)((char*)Pl + (16 + lo)*80 + lg*16);
    #pragma unroll
    for(int nj = 0; nj < 6; nj++){
      int d = w*96 + nj*16 + lo;
      bf16x8 vb = *(const bf16x8*)((char*)Vs + d*64 + lg*16);
      ctx[0][nj] = mfma_bf16(pa0, vb, ctx[0][nj]);
      ctx[1][nj] = mfma_bf16(pa1, vb, ctx[1][nj]);
    }
  }
  #pragma unroll
  for(int i = 0; i < 4; i++){
    float v = ps[i];
    v += __shfl_xor(v, 1); v += __shfl_xor(v, 2);
    v += __shfl_xor(v, 4); v += __shfl_xor(v, 8);
    if(lo == 0) sums[ni][mi*16 + lg*4 + i] = v;
  }
  __syncthreads();
  const int b = bh >> 2, h = bh & 3;
  #pragma unroll
  for(int m2 = 0; m2 < 2; m2++){
    #pragma unroll
    for(int i = 0; i < 4; i++){
      int ql = m2*16 + lg*4 + i;
      int q = q0 + ql;
      if(q >= SEQ) continue;
      float inv = 1.0f / (sums[0][ql] + sums[1][ql]);
      #pragma unroll
      for(int nj = 0; nj < 6; nj++){
        int d = w*96 + nj*16 + lo;
        out[((size_t)(b*SEQ + q))*DM + h*DH + d] = ctx[m2][nj][i] * inv;
      }
    }
  }
}

extern "C" void kernel_launch(void* const* d_in, const int* in_sizes, int n_in,
                              void* d_out, int out_size, void* d_ws, size_t ws_size,
                              hipStream_t stream){
  const float* X  = (const float*)d_in[0];
  const float* qw = (const float*)d_in[1];
  const float* kw = (const float*)d_in[2];
  const float* vw = (const float*)d_in[3];
  const float* de = (const float*)d_in[4];
  float* out = (float*)d_out;
  char* ws = (char*)d_ws;

  // ws layout (bytes):
  // [0, 11304960)           Qb  bf16 (bh,s,d)
  // [11304960, 22609920)    Kb  bf16 (bh,s,d)
  // [22609920, 33914880)    Vt  bf16 (bh,d,s)
  // [33914880, 35327232)    Eb  bf16 (1839x384)
  // [35327232, 62412032)    regionR: Xb(11.3M)+Wt(14.2M) during proj, then relS(27.1M)
  unsigned short* Qb   = (unsigned short*)ws;
  unsigned short* Kb   = (unsigned short*)(ws + 11304960);
  unsigned short* Vt   = (unsigned short*)(ws + 22609920);
  unsigned short* Eb   = (unsigned short*)(ws + 33914880);
  char* regionR        = ws + 35327232;
  unsigned short* relS = (unsigned short*)regionR;
  unsigned short* Xb   = (unsigned short*)regionR;
  unsigned short* Wt   = (unsigned short*)(regionR + 11304960);

  k_f2bf<<<dim3(2048), dim3(256), 0, stream>>>(X,  Xb, MTOK*DM);
  k_f2bf<<<dim3(690),  dim3(256), 0, stream>>>(de, Eb, NREL*DH);
  k_wt3<<<dim3(48,48,3), dim3(32,8), 0, stream>>>(qw, kw, vw, Wt);
  k_proj<<<dim3(480), dim3(512), 0, stream>>>(Xb, Wt, Qb, Kb, Vt);
  k_rel<<<dim3(77,10), dim3(512), 0, stream>>>(Qb, Eb, relS);   // overwrites Xb/Wt (dead)
  k_attn<<<dim3(29,16), dim3(256), 0, stream>>>(Qb, Kb, Vt, relS, out);
}